// Round 14
// baseline (92.752 us; speedup 1.0000x reference)
//
#include <hip/hip_runtime.h>

#define NBATCH 8192
#define NELEC  16
#define NMO    32
#define NCONF  64
#define NS     8          // NUP == NDOWN == 8
#define TSTR   20         // A (fp32) row stride in floats (80 B: 16B-aligned for b128)
#define TSZ    (NMO * TSTR)
#define TSTRH  24         // D (fp16) row stride in HALVES (48 B: 16B-aligned for b128)
#define TSZH   (NMO * TSTRH)

typedef float    v2f   __attribute__((ext_vector_type(2)));
typedef _Float16 half8 __attribute__((ext_vector_type(8)));

__device__ __forceinline__ v2f pkfma(v2f a, v2f b, v2f c) {
#if __has_builtin(__builtin_elementwise_fma)
    return __builtin_elementwise_fma(a, b, c);
#else
    return a * b + c;
#endif
}
__device__ __forceinline__ v2f bc2(float s) { return (v2f){s, s}; }
__device__ __forceinline__ float getel2(const v2f (&R)[4], int j) {
    return (j & 1) ? R[j >> 1].y : R[j >> 1].x;
}
__device__ __forceinline__ void setel2(v2f (&R)[4], int j, float v) {
    if (j & 1) R[j >> 1].y = v; else R[j >> 1].x = v;
}

// PROVEN solve (absmax 20288 since R7/R12): fp32 A from LDS, fp16 D from LDS
// (D enters linearly -> no kappa amplification; R11 proved fp16-A fails at
// 4e8). In-place no-pivot LU packed over column pairs; tr = sum_k
// <col_k(A'^-1), row_k(D')>, unit-RHS solves packed over k pairs.
// R3/R4 lesson: rows of D' pair with columns of A'^-1 — keep this pairing.
__device__ __forceinline__ void solve8T(const float* __restrict__ MOT,
                                        const _Float16* __restrict__ D2T,
                                        const int (&cols)[NS], int eoff,
                                        float& det_out, float& tr_out)
{
    v2f A2[NS][4];                    // row j, pair p = cols {2p, 2p+1}
    #pragma unroll
    for (int j = 0; j < NS; ++j) {
        const float4* pa = (const float4*)(MOT + cols[j] * TSTR + eoff);
        float4 a0 = pa[0], a1 = pa[1];
        A2[j][0] = (v2f){a0.x, a0.y};
        A2[j][1] = (v2f){a0.z, a0.w};
        A2[j][2] = (v2f){a1.x, a1.y};
        A2[j][3] = (v2f){a1.z, a1.w};
    }

    float det = 1.0f;
    #pragma unroll
    for (int k = 0; k < NS; ++k) {
        float ukk = getel2(A2[k], k);
        det *= ukk;
        float pinv = __builtin_amdgcn_rcpf(ukk);
        #pragma unroll
        for (int r = k + 1; r < NS; ++r) {
            float m = getel2(A2[r], k) * pinv;
            v2f m2 = bc2(m);
            #pragma unroll
            for (int p = (k + 1) >> 1; p < 4; ++p)
                A2[r][p] = pkfma(-m2, A2[k][p], A2[r][p]);
            setel2(A2[r], k, m);
        }
        setel2(A2[k], k, pinv);
    }

    float tr = 0.0f;
    #pragma unroll
    for (int t = 0; t < 4; ++t) {
        const int k0 = 2 * t, k1 = 2 * t + 1;

        half8 hd0 = *(const half8*)(D2T + cols[k0] * TSTRH + eoff);
        half8 hd1 = *(const half8*)(D2T + cols[k1] * TSTRH + eoff);

        v2f y2[NS];
        y2[k0] = (v2f){1.0f, 0.0f};
        y2[k1] = (v2f){-getel2(A2[k1], k0), 1.0f};
        #pragma unroll
        for (int i = k1 + 1; i < NS; ++i) {
            v2f acc = (v2f){0.0f, 0.0f};
            #pragma unroll
            for (int j = k0; j < i; ++j)
                acc = pkfma(bc2(getel2(A2[i], j)), y2[j], acc);
            y2[i] = -acc;
        }

        v2f x2[NS];
        #pragma unroll
        for (int i = NS - 1; i >= 0; --i) {
            v2f acc = (i >= k0) ? y2[i] : (v2f){0.0f, 0.0f};
            #pragma unroll
            for (int c2 = i + 1; c2 < NS; ++c2)
                acc = pkfma(-bc2(getel2(A2[i], c2)), x2[c2], acc);
            x2[i] = acc * bc2(getel2(A2[i], i));
        }

        #pragma unroll
        for (int i = 0; i < NS; ++i) {
            tr = fmaf(x2[i].x, (float)hd0[i], tr);
            tr = fmaf(x2[i].y, (float)hd1[i], tr);
        }
    }

    det_out = det;
    tr_out  = tr;
}

// R14: SINGLE-WAVE BLOCKS — the one residency axis never tested (R9 went
// bigger, R10 went persistent; both neutral/regress). One 64-thread block per
// batch, one thread per config doing BOTH spins sequentially (dual-chain ILP
// in-thread, no shfl epilogue). Rationale: multi-wave blocks couple all waves
// to the slowest staging load at the barrier, and block-generations serialize
// staging-latency behind compute. Many small independent blocks per CU
// stagger their staging/compute phases -> cross-block overlap the previous
// structures couldn't express. LDS only 4.1 KB, VGPR unconstrained by bound.
__global__ __launch_bounds__(64)
void kp_w1_kernel(const float* __restrict__ MO,
                  const float* __restrict__ d2MO,
                  const int*   __restrict__ cfg_up,
                  const int*   __restrict__ cfg_dn,
                  float*       __restrict__ out)
{
    __shared__ float    smA[TSZ];            // MO^T fp32, 32 x 20
    __shared__ _Float16 smD[TSZH];           // d2MO^T fp16, 32 x 24

    const int w = threadIdx.x;               // 0..63
    const int b = blockIdx.x;                // one batch per block

    const float* MOb = MO   + (size_t)b * NELEC * NMO;
    const float* d2b = d2MO + (size_t)b * NELEC * NMO;

    // Stage MO^T (fp32) + d2MO^T (fp16): 64 threads x 2 rows x 4 cols each.
    {
        const int c = (w & 7) * 4;
        #pragma unroll
        for (int rr = 0; rr < 2; ++rr) {
            const int r = (w >> 3) + rr * 8; // rows 0..7 then 8..15
            float4 v = *(const float4*)(MOb + r * NMO + c);
            float4 d = *(const float4*)(d2b + r * NMO + c);
            smA[(c + 0) * TSTR + r] = v.x;
            smA[(c + 1) * TSTR + r] = v.y;
            smA[(c + 2) * TSTR + r] = v.z;
            smA[(c + 3) * TSTR + r] = v.w;
            smD[(c + 0) * TSTRH + r] = (_Float16)d.x;
            smD[(c + 1) * TSTRH + r] = (_Float16)d.y;
            smD[(c + 2) * TSTRH + r] = (_Float16)d.z;
            smD[(c + 3) * TSTRH + r] = (_Float16)d.w;
        }
    }
    __syncthreads();                         // single-wave block: cheap

    // configs: row w is 8 ints = 32 B -> two int4 loads per spin
    int4 u0 = ((const int4*)cfg_up)[w * 2 + 0];
    int4 u1 = ((const int4*)cfg_up)[w * 2 + 1];
    int4 d0 = ((const int4*)cfg_dn)[w * 2 + 0];
    int4 d1 = ((const int4*)cfg_dn)[w * 2 + 1];
    const int cu[NS] = {u0.x, u0.y, u0.z, u0.w, u1.x, u1.y, u1.z, u1.w};
    const int cd[NS] = {d0.x, d0.y, d0.z, d0.w, d1.x, d1.y, d1.z, d1.w};

    float detU, trU, detD, trD;
    solve8T(smA, smD, cu, 0,  detU, trU);
    solve8T(smA, smD, cd, NS, detD, trD);

    out[(size_t)b * NCONF + w] = -0.5f * (trU + trD) * detU * detD;
}

extern "C" void kernel_launch(void* const* d_in, const int* in_sizes, int n_in,
                              void* d_out, int out_size, void* d_ws, size_t ws_size,
                              hipStream_t stream)
{
    const float* MO     = (const float*)d_in[0];
    const float* d2MO   = (const float*)d_in[1];
    const int*   cfg_up = (const int*)d_in[2];
    const int*   cfg_dn = (const int*)d_in[3];
    float* out = (float*)d_out;

    dim3 grid(NBATCH);   // 8192 single-wave blocks, one batch each
    dim3 block(64);
    kp_w1_kernel<<<grid, block, 0, stream>>>(MO, d2MO, cfg_up, cfg_dn, out);
}

// Round 15
// 89.516 us; speedup vs baseline: 1.0361x; 1.0361x over previous
//
#include <hip/hip_runtime.h>

#define NBATCH 8192
#define NELEC  16
#define NMO    32
#define NCONF  64
#define NS     8          // NUP == NDOWN == 8
#define TSTR   20         // A (fp32) row stride in floats (80 B: 16B-aligned for b128)
#define TSZ    (NMO * TSTR)
#define TSTRH  24         // D (fp16) row stride in HALVES (48 B: 16B-aligned for b128)
#define TSZH   (NMO * TSTRH)

typedef float    v2f   __attribute__((ext_vector_type(2)));
typedef _Float16 half8 __attribute__((ext_vector_type(8)));
typedef _Float16 half4 __attribute__((ext_vector_type(4)));

__device__ __forceinline__ v2f pkfma(v2f a, v2f b, v2f c) {
#if __has_builtin(__builtin_elementwise_fma)
    return __builtin_elementwise_fma(a, b, c);
#else
    return a * b + c;
#endif
}
__device__ __forceinline__ v2f bc2(float s) { return (v2f){s, s}; }
__device__ __forceinline__ float getel2(const v2f (&R)[4], int j) {
    return (j & 1) ? R[j >> 1].y : R[j >> 1].x;
}
__device__ __forceinline__ void setel2(v2f (&R)[4], int j, float v) {
    if (j & 1) R[j >> 1].y = v; else R[j >> 1].x = v;
}

// PROVEN solve (absmax 20288 since R7/R12, byte-identical here): fp32 A from
// LDS, fp16 D from LDS (D enters linearly -> no kappa amplification; R11
// proved fp16-A fails at 4e8). In-place no-pivot LU packed over column pairs;
// tr = sum_k <col_k(A'^-1), row_k(D')>, unit-RHS solves packed over k pairs.
// R3/R4 lesson: rows of D' pair with columns of A'^-1 — keep this pairing.
__device__ __forceinline__ void solve8T(const float* __restrict__ MOT,
                                        const _Float16* __restrict__ D2T,
                                        const int (&cols)[NS], int eoff,
                                        float& det_out, float& tr_out)
{
    v2f A2[NS][4];                    // row j, pair p = cols {2p, 2p+1}
    #pragma unroll
    for (int j = 0; j < NS; ++j) {
        const float4* pa = (const float4*)(MOT + cols[j] * TSTR + eoff);
        float4 a0 = pa[0], a1 = pa[1];
        A2[j][0] = (v2f){a0.x, a0.y};
        A2[j][1] = (v2f){a0.z, a0.w};
        A2[j][2] = (v2f){a1.x, a1.y};
        A2[j][3] = (v2f){a1.z, a1.w};
    }

    float det = 1.0f;
    #pragma unroll
    for (int k = 0; k < NS; ++k) {
        float ukk = getel2(A2[k], k);
        det *= ukk;
        float pinv = __builtin_amdgcn_rcpf(ukk);
        #pragma unroll
        for (int r = k + 1; r < NS; ++r) {
            float m = getel2(A2[r], k) * pinv;
            v2f m2 = bc2(m);
            #pragma unroll
            for (int p = (k + 1) >> 1; p < 4; ++p)
                A2[r][p] = pkfma(-m2, A2[k][p], A2[r][p]);
            setel2(A2[r], k, m);
        }
        setel2(A2[k], k, pinv);
    }

    float tr = 0.0f;
    #pragma unroll
    for (int t = 0; t < 4; ++t) {
        const int k0 = 2 * t, k1 = 2 * t + 1;

        half8 hd0 = *(const half8*)(D2T + cols[k0] * TSTRH + eoff);
        half8 hd1 = *(const half8*)(D2T + cols[k1] * TSTRH + eoff);

        v2f y2[NS];
        y2[k0] = (v2f){1.0f, 0.0f};
        y2[k1] = (v2f){-getel2(A2[k1], k0), 1.0f};
        #pragma unroll
        for (int i = k1 + 1; i < NS; ++i) {
            v2f acc = (v2f){0.0f, 0.0f};
            #pragma unroll
            for (int j = k0; j < i; ++j)
                acc = pkfma(bc2(getel2(A2[i], j)), y2[j], acc);
            y2[i] = -acc;
        }

        v2f x2[NS];
        #pragma unroll
        for (int i = NS - 1; i >= 0; --i) {
            v2f acc = (i >= k0) ? y2[i] : (v2f){0.0f, 0.0f};
            #pragma unroll
            for (int c2 = i + 1; c2 < NS; ++c2)
                acc = pkfma(-bc2(getel2(A2[i], c2)), x2[c2], acc);
            x2[i] = acc * bc2(getel2(A2[i], i));
        }

        #pragma unroll
        for (int i = 0; i < NS; ++i) {
            tr = fmaf(x2[i].x, (float)hd0[i], tr);
            tr = fmaf(x2[i].y, (float)hd1[i], tr);
        }
    }

    det_out = det;
    tr_out  = tr;
}

// R15: KILL THE TRANSPOSED LDS SCATTER. R2-R14 staging did 16 ds_write_b32
// per thread at an intrinsic 4-way bank conflict (banks {r,16+r}) ~= 300
// cyc/wave — as expensive as the whole read phase, and never counted until
// now (DS pipe total ~18 us/CU busy ~= the 34 us kernel invariant).
// New mapping: thread u global-loads COLUMN mo=u&31, elecs e4..e4+3
// (each inst = 2 cache lines per wave, coalesced at line granularity, same
// HBM bytes), so the thread holds MOT[mo][e4..e4+3] contiguously ->
// staging = ONE ds_write_b128 (A) + ONE ds_write_b64 (D) per thread.
// Read side + solve byte-identical to R12 (best: 89.3 us).
__global__ __launch_bounds__(256)
void kp_wb_kernel(const float* __restrict__ MO,
                  const float* __restrict__ d2MO,
                  const int*   __restrict__ cfg_up,
                  const int*   __restrict__ cfg_dn,
                  float*       __restrict__ out)
{
    __shared__ float    smA[2][TSZ];         // [batch-half][MO^T fp32, 32 x 20]
    __shared__ _Float16 smD[2][TSZH];        // [batch-half][d2MO^T fp16, 32 x 24]

    const int tid  = threadIdx.x;
    const int half = tid >> 7;               // batch within block (0/1)
    const int u    = tid & 127;              // id within the batch's 128 threads
    const int b    = blockIdx.x * 2 + half;  // batch index

    float*    MOT = smA[half];
    _Float16* D2T = smD[half];

    const float* MOb = MO   + (size_t)b * NELEC * NMO;
    const float* d2b = d2MO + (size_t)b * NELEC * NMO;

    // Stage: thread u covers (mo = u&31, elecs e4..e4+3), e4 = (u>>5)*4.
    // 4+4 scalar global loads (per inst: lanes 0-31 sweep one full MO row =
    // one 128B line; lanes 32-63 another -> 2 lines/inst, fully coalesced),
    // then one contiguous b128 (A) + b64 (D) LDS write. 16B/8B alignment:
    // mo*80 + e4*4 and mo*48 + e4*2 with e4 in {0,4,8,12}.  [vs R12: 16
    // conflicted ds_write_b32]
    {
        const int mo = u & 31;
        const int e4 = (u >> 5) * 4;
        float  a0 = MOb[(e4 + 0) * NMO + mo];
        float  a1 = MOb[(e4 + 1) * NMO + mo];
        float  a2 = MOb[(e4 + 2) * NMO + mo];
        float  a3 = MOb[(e4 + 3) * NMO + mo];
        float  d0 = d2b[(e4 + 0) * NMO + mo];
        float  d1 = d2b[(e4 + 1) * NMO + mo];
        float  d2 = d2b[(e4 + 2) * NMO + mo];
        float  d3 = d2b[(e4 + 3) * NMO + mo];
        *(float4*)(MOT + mo * TSTR + e4) = (float4){a0, a1, a2, a3};
        *(half4*)(D2T + mo * TSTRH + e4) =
            (half4){(_Float16)d0, (_Float16)d1, (_Float16)d2, (_Float16)d3};
    }
    __syncthreads();

    const int cidx = u >> 1;                 // config index 0..63
    const int s    = u & 1;                  // 0 = up, 1 = down
    const int* cfg = s ? cfg_dn : cfg_up;
    int4 c0 = ((const int4*)cfg)[cidx * 2 + 0];
    int4 c1 = ((const int4*)cfg)[cidx * 2 + 1];
    const int cols[NS] = {c0.x, c0.y, c0.z, c0.w, c1.x, c1.y, c1.z, c1.w};

    float det, tr;
    solve8T(MOT, D2T, cols, s * NS, det, tr);

    // partner lane (u^1, same wave) holds the other spin channel
    float det_o = __shfl_xor(det, 1);
    float tr_o  = __shfl_xor(tr, 1);
    if (s == 0)
        out[(size_t)b * NCONF + cidx] = -0.5f * (tr + tr_o) * det * det_o;
}

extern "C" void kernel_launch(void* const* d_in, const int* in_sizes, int n_in,
                              void* d_out, int out_size, void* d_ws, size_t ws_size,
                              hipStream_t stream)
{
    const float* MO     = (const float*)d_in[0];
    const float* d2MO   = (const float*)d_in[1];
    const int*   cfg_up = (const int*)d_in[2];
    const int*   cfg_dn = (const int*)d_in[3];
    float* out = (float*)d_out;

    dim3 grid(NBATCH / 2);   // 4096 blocks, 2 batches per block, 2 threads per pair
    dim3 block(256);
    kp_wb_kernel<<<grid, block, 0, stream>>>(MO, d2MO, cfg_up, cfg_dn, out);
}